// Round 1
// baseline (2672.832 us; speedup 1.0000x reference)
//
#include <hip/hip_runtime.h>
#include <hip/hip_bf16.h>

// Problem constants
//   B=128, N=1024, E=16384, ENTITY=100000, EMB=100, HID=100

__device__ __forceinline__ float bflo(unsigned int u) {
    union { unsigned int i; float f; } v; v.i = u << 16; return v.f;
}
__device__ __forceinline__ float bfhi(unsigned int u) {
    union { unsigned int i; float f; } v; v.i = u & 0xffff0000u; return v.f;
}
__device__ __forceinline__ unsigned int f2bf1(float f) {
    union { float f; unsigned int u; } v; v.f = f;
    return (v.u + 0x7fffu + ((v.u >> 16) & 1u)) >> 16;   // RNE
}
__device__ __forceinline__ unsigned int packbf(float a, float b) {
    return f2bf1(a) | (f2bf1(b) << 16);
}
__device__ __forceinline__ float sigm(float x) { return 1.f / (1.f + __expf(-x)); }
__device__ __forceinline__ float tanh_fast(float x) {
    float e = __expf(2.f * x);
    return 1.f - 2.f / (e + 1.f);
}

// ---------------------------------------------------------------------------
// Kernel 1: embedding gather + GCN matmul.  support[n][h] (bf16 packed u32)
// thread-per-node, acc[100] in VGPRs, gcn_w broadcast from LDS.
// ---------------------------------------------------------------------------
__global__ __launch_bounds__(256, 2)
void gcn_kernel(const int* __restrict__ nb, const float* __restrict__ emb,
                const float* __restrict__ w, unsigned int* __restrict__ support)
{
    __shared__ float wl[10000];                 // w[k][h], 40 KB
    for (int i = threadIdx.x; i < 10000; i += 256) wl[i] = w[i];
    __syncthreads();

    const int n = blockIdx.x * 256 + threadIdx.x;        // 0..131071
    const long long row = nb[n];
    const float4* __restrict__ xr = (const float4*)(emb + row * 100);

    float acc[100];
#pragma unroll
    for (int h = 0; h < 100; ++h) acc[h] = 0.f;

    for (int kk = 0; kk < 25; ++kk) {
        const float4 xv = xr[kk];
        const float xs[4] = { xv.x, xv.y, xv.z, xv.w };
#pragma unroll
        for (int q = 0; q < 4; ++q) {
            const float* wrow = &wl[(kk * 4 + q) * 100];
            const float xq = xs[q];
#pragma unroll
            for (int h4 = 0; h4 < 25; ++h4) {
                const float4 w4 = *(const float4*)(wrow + h4 * 4);
                acc[h4*4+0] = fmaf(xq, w4.x, acc[h4*4+0]);
                acc[h4*4+1] = fmaf(xq, w4.y, acc[h4*4+1]);
                acc[h4*4+2] = fmaf(xq, w4.z, acc[h4*4+2]);
                acc[h4*4+3] = fmaf(xq, w4.w, acc[h4*4+3]);
            }
        }
    }

    unsigned int* __restrict__ o = support + (size_t)n * 50;
#pragma unroll
    for (int i = 0; i < 50; ++i) o[i] = packbf(acc[2*i], acc[2*i+1]);
}

// ---------------------------------------------------------------------------
// Kernel 2: per-sample SpMM.  seq[b][r][:] = sum_e val*support[b][col][:] + gcn_b
// block = (row-chunk of 128, sample).  LDS fp32 accumulator (pad 101),
// queue-compacted edges, LDS float atomics.
// ---------------------------------------------------------------------------
__global__ __launch_bounds__(256, 2)
void spmm_kernel(const int* __restrict__ arow, const int* __restrict__ acol,
                 const float* __restrict__ aval, const unsigned int* __restrict__ support,
                 const float* __restrict__ gcn_b, unsigned int* __restrict__ seq)
{
    __shared__ float acc[128 * 101];            // 51,712 B
    __shared__ int   qrel[1024];
    __shared__ int   qcol[1024];
    __shared__ float qval[1024];
    __shared__ int   qn;

    const int b  = blockIdx.y;
    const int r0 = blockIdx.x * 128;

    for (int i = threadIdx.x; i < 128 * 101; i += 256) acc[i] = 0.f;
    if (threadIdx.x == 0) qn = 0;
    __syncthreads();

    const int*   rw = arow + b * 16384;
    const int*   cl = acol + b * 16384;
    const float* vl = aval + b * 16384;
    const unsigned int* supb = support + (size_t)b * 1024 * 50;

    for (int g = 0; g < 16; ++g) {              // 16 groups x 1024 edges
#pragma unroll
        for (int bb = 0; bb < 4; ++bb) {
            const int e = (g * 4 + bb) * 256 + threadIdx.x;
            const int r = rw[e];
            const unsigned int rel = (unsigned int)(r - r0);
            if (rel < 128u) {
                const int idx = atomicAdd(&qn, 1);   // capacity 1024 == max appends/group
                qrel[idx] = (int)rel; qcol[idx] = cl[e]; qval[idx] = vl[e];
            }
        }
        __syncthreads();
        const int nq = qn;
        for (int i = threadIdx.x; i < nq; i += 256) {
            const int rel = qrel[i];
            const unsigned int* sp = supb + (size_t)qcol[i] * 50;
            const float v = qval[i];
            float* ar = &acc[rel * 101];
#pragma unroll
            for (int hh = 0; hh < 50; ++hh) {
                const unsigned int u = sp[hh];
                atomicAdd(&ar[2*hh],     v * bflo(u));
                atomicAdd(&ar[2*hh + 1], v * bfhi(u));
            }
        }
        __syncthreads();
        if (threadIdx.x == 0) qn = 0;
        __syncthreads();
    }

    unsigned int* sq = seq + ((size_t)b * 1024 + r0) * 50;
    for (int i = threadIdx.x; i < 6400; i += 256) {
        const int r = i / 50, h2 = i % 50;
        const float a0 = acc[r*101 + 2*h2]     + gcn_b[2*h2];
        const float a1 = acc[r*101 + 2*h2 + 1] + gcn_b[2*h2 + 1];
        sq[(size_t)r * 50 + h2] = packbf(a0, a1);
    }
}

// ---------------------------------------------------------------------------
// Kernel 3: gx GEMM for one time-chunk.  gx[m][g*100+jj] = seq[m]·w_ih[g*100+jj] + b_ih
// block = (gate, 256-row tile); thread-per-row, acc[100], transposed w_ih in LDS.
// ---------------------------------------------------------------------------
__global__ __launch_bounds__(256, 2)
void gx_gemm(const unsigned int* __restrict__ seq, const float* __restrict__ w_ih,
             const float* __restrict__ b_ih, float* __restrict__ gx,
             int c0, int ctl, int CT)
{
    __shared__ float wl[10000];                 // wl[k*100+jj] = w_ih[(g*100+jj)*100+k]
    const int g    = blockIdx.x % 3;
    const int tile = blockIdx.x / 3;

    for (int i = threadIdx.x; i < 10000; i += 256) {
        // (g*100+jj)*100+k == g*10000 + i  with k=i%100, jj=i/100 -> coalesced read
        wl[(i % 100) * 100 + (i / 100)] = w_ih[g * 10000 + i];
    }
    __syncthreads();

    const int m = tile * 256 + threadIdx.x;     // 0 .. B*CT-1
    const int b = m >> ctl;
    const int t = m & (CT - 1);
    const unsigned int* sr = seq + ((size_t)b * 1024 + c0 + t) * 50;
    const uint2* sr2 = (const uint2*)sr;

    float acc[100];
    const float4* bi4 = (const float4*)(b_ih + g * 100);
#pragma unroll
    for (int j4 = 0; j4 < 25; ++j4) {
        const float4 bv = bi4[j4];
        acc[j4*4+0] = bv.x; acc[j4*4+1] = bv.y; acc[j4*4+2] = bv.z; acc[j4*4+3] = bv.w;
    }

    for (int kk = 0; kk < 25; ++kk) {
        const uint2 up = sr2[kk];
        const float xs[4] = { bflo(up.x), bfhi(up.x), bflo(up.y), bfhi(up.y) };
#pragma unroll
        for (int q = 0; q < 4; ++q) {
            const float* wrow = &wl[(kk * 4 + q) * 100];
            const float xq = xs[q];
#pragma unroll
            for (int j4 = 0; j4 < 25; ++j4) {
                const float4 w4 = *(const float4*)(wrow + j4 * 4);
                acc[j4*4+0] = fmaf(xq, w4.x, acc[j4*4+0]);
                acc[j4*4+1] = fmaf(xq, w4.y, acc[j4*4+1]);
                acc[j4*4+2] = fmaf(xq, w4.z, acc[j4*4+2]);
                acc[j4*4+3] = fmaf(xq, w4.w, acc[j4*4+3]);
            }
        }
    }

    float4* og = (float4*)(gx + (size_t)m * 300 + g * 100);
#pragma unroll
    for (int j4 = 0; j4 < 25; ++j4)
        og[j4] = make_float4(acc[j4*4+0], acc[j4*4+1], acc[j4*4+2], acc[j4*4+3]);
}

// ---------------------------------------------------------------------------
// Kernel 4: GRU recurrence over one time-chunk + (last) FC head.
// block-per-sample, 384 threads; thread j<300 holds w_hh row j in registers.
// ---------------------------------------------------------------------------
__global__ __launch_bounds__(384, 1)
void gru_kernel(const float* __restrict__ gx, const float* __restrict__ w_hh,
                const float* __restrict__ b_hh, float* __restrict__ hg,
                const float* __restrict__ fc1_w, const float* __restrict__ fc1_b,
                float* __restrict__ out, int first, int last, int CT)
{
    __shared__ float h_lds[100];
    __shared__ float gh_l[300];
    __shared__ float gx_l[300];

    const int b = blockIdx.x;
    const int j = threadIdx.x;

    float wr[100];
    float bh = 0.f;
    if (j < 300) {
        const float4* wrow = (const float4*)(w_hh + j * 100);
#pragma unroll
        for (int kk = 0; kk < 25; ++kk) {
            const float4 wv = wrow[kk];
            wr[kk*4+0] = wv.x; wr[kk*4+1] = wv.y; wr[kk*4+2] = wv.z; wr[kk*4+3] = wv.w;
        }
        bh = b_hh[j];
    }
    if (j < 100) h_lds[j] = first ? 0.f : hg[b * 100 + j];
    __syncthreads();

    const float* gxb = gx + (size_t)b * CT * 300;
    float gxv = (j < 300) ? gxb[j] : 0.f;       // prefetched t=0

    for (int t = 0; t < CT; ++t) {
        float gnext = 0.f;
        if (j < 300) {
            const int tn = (t + 1 < CT) ? (t + 1) : t;
            gnext = gxb[(size_t)tn * 300 + j];  // prefetch next step (hidden under dot)

            float s0 = 0.f, s1 = 0.f, s2 = 0.f, s3 = 0.f;
#pragma unroll
            for (int kk = 0; kk < 25; ++kk) {
                const float4 hv = *(const float4*)&h_lds[kk * 4];
                s0 = fmaf(wr[kk*4+0], hv.x, s0);
                s1 = fmaf(wr[kk*4+1], hv.y, s1);
                s2 = fmaf(wr[kk*4+2], hv.z, s2);
                s3 = fmaf(wr[kk*4+3], hv.w, s3);
            }
            gh_l[j] = (s0 + s1) + (s2 + s3) + bh;
            gx_l[j] = gxv;
        }
        __syncthreads();
        if (j < 100) {
            const float r = sigm(gx_l[j]       + gh_l[j]);
            const float z = sigm(gx_l[100 + j] + gh_l[100 + j]);
            const float n = tanh_fast(gx_l[200 + j] + r * gh_l[200 + j]);
            h_lds[j] = (1.f - z) * n + z * h_lds[j];
        }
        __syncthreads();
        gxv = gnext;
    }

    if (j < 100) {
        hg[b * 100 + j] = h_lds[j];
        if (last) {
            const float4* fw = (const float4*)(fc1_w + j * 100);
            float s0 = 0.f, s1 = 0.f, s2 = 0.f, s3 = 0.f;
#pragma unroll
            for (int kk = 0; kk < 25; ++kk) {
                const float4 wv = fw[kk];
                const float4 hv = *(const float4*)&h_lds[kk * 4];
                s0 = fmaf(wv.x, hv.x, s0);
                s1 = fmaf(wv.y, hv.y, s1);
                s2 = fmaf(wv.z, hv.z, s2);
                s3 = fmaf(wv.w, hv.w, s3);
            }
            const float s = (s0 + s1) + (s2 + s3) + fc1_b[j];
            out[b * 100 + j] = fmaxf(s, 0.f);
        }
    }
}

// ---------------------------------------------------------------------------
extern "C" void kernel_launch(void* const* d_in, const int* in_sizes, int n_in,
                              void* d_out, int out_size, void* d_ws, size_t ws_size,
                              hipStream_t stream)
{
    const int*   neighbors = (const int*)  d_in[0];
    const int*   adj_row   = (const int*)  d_in[1];
    const int*   adj_col   = (const int*)  d_in[2];
    const float* adj_val   = (const float*)d_in[3];
    const float* emb       = (const float*)d_in[4];
    const float* gcn_w     = (const float*)d_in[5];
    const float* gcn_b     = (const float*)d_in[6];
    const float* w_ih      = (const float*)d_in[7];
    const float* w_hh      = (const float*)d_in[8];
    const float* b_ih      = (const float*)d_in[9];
    const float* b_hh      = (const float*)d_in[10];
    const float* fc1_w     = (const float*)d_in[11];
    const float* fc1_b     = (const float*)d_in[12];
    float* out = (float*)d_out;

    char* ws = (char*)d_ws;
    const size_t support_bytes = (size_t)128 * 1024 * 100 * 2;   // 26,214,400 (bf16)
    const size_t seq_bytes     = support_bytes;                  // 26,214,400 (bf16)

    unsigned int* support = (unsigned int*)ws;
    unsigned int* seq     = (unsigned int*)(ws + support_bytes);

    // pick the largest time-chunk that fits the workspace
    int CT = 256, ctl = 8;
    while (CT > 8 &&
           support_bytes + seq_bytes + (size_t)128 * CT * 300 * 4 + 51200 > ws_size) {
        CT >>= 1; --ctl;
    }
    float* gx = (float*)(ws + support_bytes + seq_bytes);
    float* hg = (float*)(ws + support_bytes + seq_bytes + (size_t)128 * CT * 300 * 4);

    gcn_kernel<<<512, 256, 0, stream>>>(neighbors, emb, gcn_w, support);
    spmm_kernel<<<dim3(8, 128), 256, 0, stream>>>(adj_row, adj_col, adj_val,
                                                  support, gcn_b, seq);

    const int nch = 1024 / CT;
    for (int c = 0; c < nch; ++c) {
        gx_gemm<<<3 * (128 * CT / 256), 256, 0, stream>>>(seq, w_ih, b_ih, gx,
                                                          c * CT, ctl, CT);
        gru_kernel<<<128, 384, 0, stream>>>(gx, w_hh, b_hh, hg, fc1_w, fc1_b, out,
                                            (c == 0) ? 1 : 0, (c == nch - 1) ? 1 : 0, CT);
    }
}

// Round 2
// 1773.787 us; speedup vs baseline: 1.5069x; 1.5069x over previous
//
#include <hip/hip_runtime.h>
#include <hip/hip_bf16.h>

// Problem constants
//   B=128, N=1024, E=16384, ENTITY=100000, EMB=100, HID=100

__device__ __forceinline__ float bflo(unsigned int u) {
    union { unsigned int i; float f; } v; v.i = u << 16; return v.f;
}
__device__ __forceinline__ float bfhi(unsigned int u) {
    union { unsigned int i; float f; } v; v.i = u & 0xffff0000u; return v.f;
}
__device__ __forceinline__ unsigned int f2bf1(float f) {
    union { float f; unsigned int u; } v; v.f = f;
    return (v.u + 0x7fffu + ((v.u >> 16) & 1u)) >> 16;   // RNE
}
__device__ __forceinline__ unsigned int packbf(float a, float b) {
    return f2bf1(a) | (f2bf1(b) << 16);
}
__device__ __forceinline__ float sigm(float x) { return 1.f / (1.f + __expf(-x)); }
__device__ __forceinline__ float tanh_fast(float x) {
    float e = __expf(2.f * x);
    return 1.f - 2.f / (e + 1.f);
}

// ---------------------------------------------------------------------------
// Kernel 1: embedding gather + GCN matmul.  support[n][h] (bf16 packed u32)
// thread-per-node, acc[100] in VGPRs, gcn_w broadcast from LDS.
// ---------------------------------------------------------------------------
__global__ __launch_bounds__(256, 2)
void gcn_kernel(const int* __restrict__ nb, const float* __restrict__ emb,
                const float* __restrict__ w, unsigned int* __restrict__ support)
{
    __shared__ float wl[10000];                 // w[k][h], 40 KB
    for (int i = threadIdx.x; i < 10000; i += 256) wl[i] = w[i];
    __syncthreads();

    const int n = blockIdx.x * 256 + threadIdx.x;        // 0..131071
    const long long row = nb[n];
    const float4* __restrict__ xr = (const float4*)(emb + row * 100);

    float acc[100];
#pragma unroll
    for (int h = 0; h < 100; ++h) acc[h] = 0.f;

    for (int kk = 0; kk < 25; ++kk) {
        const float4 xv = xr[kk];
        const float xs[4] = { xv.x, xv.y, xv.z, xv.w };
#pragma unroll
        for (int q = 0; q < 4; ++q) {
            const float* wrow = &wl[(kk * 4 + q) * 100];
            const float xq = xs[q];
#pragma unroll
            for (int h4 = 0; h4 < 25; ++h4) {
                const float4 w4 = *(const float4*)(wrow + h4 * 4);
                acc[h4*4+0] = fmaf(xq, w4.x, acc[h4*4+0]);
                acc[h4*4+1] = fmaf(xq, w4.y, acc[h4*4+1]);
                acc[h4*4+2] = fmaf(xq, w4.z, acc[h4*4+2]);
                acc[h4*4+3] = fmaf(xq, w4.w, acc[h4*4+3]);
            }
        }
    }

    unsigned int* __restrict__ o = support + (size_t)n * 50;
#pragma unroll
    for (int i = 0; i < 50; ++i) o[i] = packbf(acc[2*i], acc[2*i+1]);
}

// ---------------------------------------------------------------------------
// Kernel 2a: counting-sort the edge list of each sample into CSR order.
// One block per sample. LDS histogram over 1024 rows -> scan -> scatter.
// csr[e] = {col, val_bits}, offs[b][r] = row start (1025 entries per sample).
// ---------------------------------------------------------------------------
__global__ __launch_bounds__(256, 2)
void csr_build(const int* __restrict__ arow, const int* __restrict__ acol,
               const float* __restrict__ aval,
               int* __restrict__ offs, int2* __restrict__ csr)
{
    __shared__ int cnt[1024];
    __shared__ int part[256];
    __shared__ int offl[1024];

    const int b   = blockIdx.x;
    const int tid = threadIdx.x;
    const int*   rw = arow + b * 16384;
    const int*   cl = acol + b * 16384;
    const float* vl = aval + b * 16384;

    for (int i = tid; i < 1024; i += 256) cnt[i] = 0;
    __syncthreads();
    for (int e = tid; e < 16384; e += 256) atomicAdd(&cnt[rw[e]], 1);
    __syncthreads();

    int c[4]; int s = 0;
#pragma unroll
    for (int q = 0; q < 4; ++q) { c[q] = cnt[tid * 4 + q]; s += c[q]; }
    part[tid] = s;
    __syncthreads();
    for (int off = 1; off < 256; off <<= 1) {
        int v = (tid >= off) ? part[tid - off] : 0;
        __syncthreads();
        part[tid] += v;
        __syncthreads();
    }
    int run = part[tid] - s;                    // exclusive base of this 4-group
#pragma unroll
    for (int q = 0; q < 4; ++q) { offl[tid * 4 + q] = run; run += c[q]; }
    __syncthreads();

    for (int i = tid; i < 1024; i += 256) offs[b * 1025 + i] = offl[i];
    if (tid == 0) offs[b * 1025 + 1024] = 16384;

    int2* cs = csr + (size_t)b * 16384;
    for (int e = tid; e < 16384; e += 256) {
        const int r   = rw[e];
        const int pos = atomicAdd(&offl[r], 1);
        int2 cv; cv.x = cl[e]; cv.y = __float_as_int(vl[e]);
        cs[pos] = cv;
    }
}

// ---------------------------------------------------------------------------
// Kernel 2b: atomic-free CSR aggregate.
// 50 lanes per row (lane = one packed bf16 h-pair), 5 rows per 256-block.
// seq[b][r][:] = sum_{e in row} val * support[b][col][:] + gcn_b
// ---------------------------------------------------------------------------
__global__ __launch_bounds__(256, 4)
void spmm_agg(const int* __restrict__ offs, const int2* __restrict__ csr,
              const unsigned int* __restrict__ support,
              const float* __restrict__ gcn_b, unsigned int* __restrict__ seq)
{
    const int b    = blockIdx.y;
    const int lr   = threadIdx.x / 50;
    const int lane = threadIdx.x % 50;
    const int r    = blockIdx.x * 5 + lr;
    if (lr >= 5 || r >= 1024) return;

    const int e0 = offs[b * 1025 + r];
    const int e1 = offs[b * 1025 + r + 1];
    const int2* __restrict__ cs = csr + (size_t)b * 16384;
    const unsigned int* __restrict__ supb = support + (size_t)b * 1024 * 50;

    float a0 = 0.f, a1 = 0.f;
    for (int e = e0; e < e1; ++e) {
        const int2 cv = cs[e];
        const float v = __int_as_float(cv.y);
        const unsigned int u = supb[(size_t)cv.x * 50 + lane];
        a0 = fmaf(v, bflo(u), a0);
        a1 = fmaf(v, bfhi(u), a1);
    }
    a0 += gcn_b[2 * lane];
    a1 += gcn_b[2 * lane + 1];
    seq[((size_t)b * 1024 + r) * 50 + lane] = packbf(a0, a1);
}

// ---------------------------------------------------------------------------
// Kernel 3: gx GEMM for one time-chunk.  gx[m][g*100+jj] = seq[m]·w_ih[g*100+jj] + b_ih
// block = (gate, 256-row tile); thread-per-row, acc[100], transposed w_ih in LDS.
// ---------------------------------------------------------------------------
__global__ __launch_bounds__(256, 2)
void gx_gemm(const unsigned int* __restrict__ seq, const float* __restrict__ w_ih,
             const float* __restrict__ b_ih, float* __restrict__ gx,
             int c0, int ctl, int CT)
{
    __shared__ float wl[10000];                 // wl[k*100+jj] = w_ih[(g*100+jj)*100+k]
    const int g    = blockIdx.x % 3;
    const int tile = blockIdx.x / 3;

    for (int i = threadIdx.x; i < 10000; i += 256) {
        wl[(i % 100) * 100 + (i / 100)] = w_ih[g * 10000 + i];
    }
    __syncthreads();

    const int m = tile * 256 + threadIdx.x;     // 0 .. B*CT-1
    const int b = m >> ctl;
    const int t = m & (CT - 1);
    const unsigned int* sr = seq + ((size_t)b * 1024 + c0 + t) * 50;
    const uint2* sr2 = (const uint2*)sr;

    float acc[100];
    const float4* bi4 = (const float4*)(b_ih + g * 100);
#pragma unroll
    for (int j4 = 0; j4 < 25; ++j4) {
        const float4 bv = bi4[j4];
        acc[j4*4+0] = bv.x; acc[j4*4+1] = bv.y; acc[j4*4+2] = bv.z; acc[j4*4+3] = bv.w;
    }

    for (int kk = 0; kk < 25; ++kk) {
        const uint2 up = sr2[kk];
        const float xs[4] = { bflo(up.x), bfhi(up.x), bflo(up.y), bfhi(up.y) };
#pragma unroll
        for (int q = 0; q < 4; ++q) {
            const float* wrow = &wl[(kk * 4 + q) * 100];
            const float xq = xs[q];
#pragma unroll
            for (int j4 = 0; j4 < 25; ++j4) {
                const float4 w4 = *(const float4*)(wrow + j4 * 4);
                acc[j4*4+0] = fmaf(xq, w4.x, acc[j4*4+0]);
                acc[j4*4+1] = fmaf(xq, w4.y, acc[j4*4+1]);
                acc[j4*4+2] = fmaf(xq, w4.z, acc[j4*4+2]);
                acc[j4*4+3] = fmaf(xq, w4.w, acc[j4*4+3]);
            }
        }
    }

    float4* og = (float4*)(gx + (size_t)m * 300 + g * 100);
#pragma unroll
    for (int j4 = 0; j4 < 25; ++j4)
        og[j4] = make_float4(acc[j4*4+0], acc[j4*4+1], acc[j4*4+2], acc[j4*4+3]);
}

// ---------------------------------------------------------------------------
// Kernel 4: GRU recurrence over one time-chunk + (last) FC head.
// block-per-sample, 384 threads; thread j<300 holds w_hh row j in registers.
// ---------------------------------------------------------------------------
__global__ __launch_bounds__(384, 1)
void gru_kernel(const float* __restrict__ gx, const float* __restrict__ w_hh,
                const float* __restrict__ b_hh, float* __restrict__ hg,
                const float* __restrict__ fc1_w, const float* __restrict__ fc1_b,
                float* __restrict__ out, int first, int last, int CT)
{
    __shared__ float h_lds[100];
    __shared__ float gh_l[300];
    __shared__ float gx_l[300];

    const int b = blockIdx.x;
    const int j = threadIdx.x;

    float wr[100];
    float bh = 0.f;
    if (j < 300) {
        const float4* wrow = (const float4*)(w_hh + j * 100);
#pragma unroll
        for (int kk = 0; kk < 25; ++kk) {
            const float4 wv = wrow[kk];
            wr[kk*4+0] = wv.x; wr[kk*4+1] = wv.y; wr[kk*4+2] = wv.z; wr[kk*4+3] = wv.w;
        }
        bh = b_hh[j];
    }
    if (j < 100) h_lds[j] = first ? 0.f : hg[b * 100 + j];
    __syncthreads();

    const float* gxb = gx + (size_t)b * CT * 300;
    float gxv = (j < 300) ? gxb[j] : 0.f;       // prefetched t=0

    for (int t = 0; t < CT; ++t) {
        float gnext = 0.f;
        if (j < 300) {
            const int tn = (t + 1 < CT) ? (t + 1) : t;
            gnext = gxb[(size_t)tn * 300 + j];  // prefetch next step (hidden under dot)

            float s0 = 0.f, s1 = 0.f, s2 = 0.f, s3 = 0.f;
#pragma unroll
            for (int kk = 0; kk < 25; ++kk) {
                const float4 hv = *(const float4*)&h_lds[kk * 4];
                s0 = fmaf(wr[kk*4+0], hv.x, s0);
                s1 = fmaf(wr[kk*4+1], hv.y, s1);
                s2 = fmaf(wr[kk*4+2], hv.z, s2);
                s3 = fmaf(wr[kk*4+3], hv.w, s3);
            }
            gh_l[j] = (s0 + s1) + (s2 + s3) + bh;
            gx_l[j] = gxv;
        }
        __syncthreads();
        if (j < 100) {
            const float r = sigm(gx_l[j]       + gh_l[j]);
            const float z = sigm(gx_l[100 + j] + gh_l[100 + j]);
            const float n = tanh_fast(gx_l[200 + j] + r * gh_l[200 + j]);
            h_lds[j] = (1.f - z) * n + z * h_lds[j];
        }
        __syncthreads();
        gxv = gnext;
    }

    if (j < 100) {
        hg[b * 100 + j] = h_lds[j];
        if (last) {
            const float4* fw = (const float4*)(fc1_w + j * 100);
            float s0 = 0.f, s1 = 0.f, s2 = 0.f, s3 = 0.f;
#pragma unroll
            for (int kk = 0; kk < 25; ++kk) {
                const float4 wv = fw[kk];
                const float4 hv = *(const float4*)&h_lds[kk * 4];
                s0 = fmaf(wv.x, hv.x, s0);
                s1 = fmaf(wv.y, hv.y, s1);
                s2 = fmaf(wv.z, hv.z, s2);
                s3 = fmaf(wv.w, hv.w, s3);
            }
            const float s = (s0 + s1) + (s2 + s3) + fc1_b[j];
            out[b * 100 + j] = fmaxf(s, 0.f);
        }
    }
}

// ---------------------------------------------------------------------------
extern "C" void kernel_launch(void* const* d_in, const int* in_sizes, int n_in,
                              void* d_out, int out_size, void* d_ws, size_t ws_size,
                              hipStream_t stream)
{
    const int*   neighbors = (const int*)  d_in[0];
    const int*   adj_row   = (const int*)  d_in[1];
    const int*   adj_col   = (const int*)  d_in[2];
    const float* adj_val   = (const float*)d_in[3];
    const float* emb       = (const float*)d_in[4];
    const float* gcn_w     = (const float*)d_in[5];
    const float* gcn_b     = (const float*)d_in[6];
    const float* w_ih      = (const float*)d_in[7];
    const float* w_hh      = (const float*)d_in[8];
    const float* b_ih      = (const float*)d_in[9];
    const float* b_hh      = (const float*)d_in[10];
    const float* fc1_w     = (const float*)d_in[11];
    const float* fc1_b     = (const float*)d_in[12];
    float* out = (float*)d_out;

    char* ws = (char*)d_ws;
    const size_t support_bytes = (size_t)128 * 1024 * 100 * 2;   // 26,214,400 (bf16)
    const size_t seq_bytes     = support_bytes;                  // 26,214,400 (bf16)
    const size_t hg_bytes      = 128 * 100 * 4;                  // 51,200
    const size_t offs_bytes    = (size_t)128 * 1025 * 4;         // 524,800
    const size_t csr_bytes     = (size_t)128 * 16384 * 8;        // 16,777,216

    unsigned int* support = (unsigned int*)ws;
    unsigned int* seq     = (unsigned int*)(ws + support_bytes);
    float*        hg      = (float*)(ws + support_bytes + seq_bytes);
    char* scratch = ws + support_bytes + seq_bytes + hg_bytes;
    const size_t scratch_avail = ws_size - (support_bytes + seq_bytes + hg_bytes);

    // CSR arrays live in scratch during the SpMM phase; gx overlays the same
    // region afterwards (disjoint lifetimes).
    int*  offs = (int*)scratch;
    int2* csr  = (int2*)(scratch + offs_bytes);
    (void)csr_bytes;

    // pick the largest time-chunk whose gx fits scratch
    int CT = 256, ctl = 8;
    while (CT > 8 && (size_t)128 * CT * 300 * 4 > scratch_avail) { CT >>= 1; --ctl; }
    float* gx = (float*)scratch;

    gcn_kernel<<<512, 256, 0, stream>>>(neighbors, emb, gcn_w, support);
    csr_build<<<128, 256, 0, stream>>>(adj_row, adj_col, adj_val, offs, csr);
    spmm_agg<<<dim3(205, 128), 256, 0, stream>>>(offs, csr, support, gcn_b, seq);

    const int nch = 1024 / CT;
    for (int c = 0; c < nch; ++c) {
        gx_gemm<<<3 * (128 * CT / 256), 256, 0, stream>>>(seq, w_ih, b_ih, gx,
                                                          c * CT, ctl, CT);
        gru_kernel<<<128, 384, 0, stream>>>(gx, w_hh, b_hh, hg, fc1_w, fc1_b, out,
                                            (c == 0) ? 1 : 0, (c == nch - 1) ? 1 : 0, CT);
    }
}